// Round 1
// baseline (423.252 us; speedup 1.0000x reference)
//
#include <hip/hip_runtime.h>

typedef __attribute__((ext_vector_type(8))) short s8b;
typedef __attribute__((ext_vector_type(4))) float f4;
typedef unsigned short u16;

__device__ __forceinline__ u16 f2bf(float f) {
  union { float f; unsigned u; } x; x.f = f;
  unsigned r = x.u + 0x7fffu + ((x.u >> 16) & 1u);
  return (u16)(r >> 16);
}

__device__ __forceinline__ void gload16(const void* g, void* l) {
  __builtin_amdgcn_global_load_lds(
      (const __attribute__((address_space(1))) void*)g,
      (__attribute__((address_space(3))) void*)l, 16, 0, 0);
}

__global__ void cvt_kernel(const float* __restrict__ in, u16* __restrict__ out, int n4) {
  int i = blockIdx.x * blockDim.x + threadIdx.x;
  if (i < n4) {
    const float4 v = ((const float4*)in)[i];
    ushort4 o;
    o.x = f2bf(v.x); o.y = f2bf(v.y); o.z = f2bf(v.z); o.w = f2bf(v.w);
    ((ushort4*)out)[i] = o;
  }
}

// C[M,N] = A[M,K] * B[N,K]^T  (both row-major bf16), fp32 accum.
// MODE 0: scatter-store qkv (bf16, [B,H,T,D] each, Q scaled by 0.125)
// MODE 1: store fp32 C row-major
#define BMT 128
#define BNT 128
#define BKT 64

template<int MODE>
__global__ __launch_bounds__(256, 2)
void gemm_bt(const u16* __restrict__ A, const u16* __restrict__ Bm,
             float* __restrict__ Cf,
             u16* __restrict__ qo, u16* __restrict__ ko, u16* __restrict__ vo,
             int M, int N, int K) {
  __shared__ u16 lds[2][2][BMT * BKT];
  const int tid = threadIdx.x;
  const int lane = tid & 63;
  const int w = tid >> 6;
  const int wr = w >> 1, wc = w & 1;
  const int bm = blockIdx.y, bn = blockIdx.x;
  const int ric = lane >> 3;          // row within 8-row staging chunk
  const int ssw = (lane & 7) ^ ric;   // pre-swizzled source slot (involution)

  const u16* Ab = A + (size_t)bm * BMT * K;
  const u16* Bb = Bm + (size_t)bn * BNT * K;

  f4 acc[4][4] = {};

  auto stage = [&](int sbuf, int kt) {
    const int ko_ = kt * BKT;
#pragma unroll
    for (int c = 0; c < 4; ++c) {
      const int rch = w * 32 + c * 8;
      gload16(Ab + (size_t)(rch + ric) * K + ko_ + ssw * 8, &lds[sbuf][0][rch * BKT]);
      gload16(Bb + (size_t)(rch + ric) * K + ko_ + ssw * 8, &lds[sbuf][1][rch * BKT]);
    }
  };

  auto compute = [&](int cbuf) {
    const u16* At = &lds[cbuf][0][0];
    const u16* Bt = &lds[cbuf][1][0];
#pragma unroll
    for (int kk = 0; kk < 2; ++kk) {
      s8b a[4], b[4];
#pragma unroll
      for (int m = 0; m < 4; ++m) {
        const int row = wr * 64 + m * 16 + (lane & 15);
        a[m] = *(const s8b*)(At + row * BKT + ((((kk << 2) + (lane >> 4)) ^ (row & 7)) << 3));
      }
#pragma unroll
      for (int n = 0; n < 4; ++n) {
        const int row = wc * 64 + n * 16 + (lane & 15);
        b[n] = *(const s8b*)(Bt + row * BKT + ((((kk << 2) + (lane >> 4)) ^ (row & 7)) << 3));
      }
#pragma unroll
      for (int m = 0; m < 4; ++m)
#pragma unroll
        for (int n = 0; n < 4; ++n)
          acc[m][n] = __builtin_amdgcn_mfma_f32_16x16x32_bf16(a[m], b[n], acc[m][n], 0, 0, 0);
    }
  };

  const int nk = K / BKT;
  stage(0, 0);
  __syncthreads();
  int buf = 0;
  for (int kt = 0; kt < nk - 1; ++kt) {
    stage(buf ^ 1, kt + 1);
    compute(buf);
    __syncthreads();
    buf ^= 1;
  }
  compute(buf);

  if (MODE == 0) {
#pragma unroll
    for (int n = 0; n < 4; ++n) {
      const int f = bn * BNT + wc * 64 + n * 16 + (lane & 15);
      const int which = f >> 10;
      const int rem = f & 1023;
      const int h = rem >> 6, d = rem & 63;
      u16* dst = which == 0 ? qo : (which == 1 ? ko : vo);
      const float sc = which == 0 ? 0.125f : 1.0f;
#pragma unroll
      for (int m = 0; m < 4; ++m) {
#pragma unroll
        for (int j = 0; j < 4; ++j) {
          const int i = bm * BMT + wr * 64 + m * 16 + (lane >> 4) * 4 + j;
          const int bb = i >> 11, t = i & 2047;
          dst[((size_t)((bb << 4) + h) * 2048 + t) * 64 + d] = f2bf(acc[m][n][j] * sc);
        }
      }
    }
  } else {
#pragma unroll
    for (int m = 0; m < 4; ++m) {
#pragma unroll
      for (int j = 0; j < 4; ++j) {
        const int i = bm * BMT + wr * 64 + m * 16 + (lane >> 4) * 4 + j;
#pragma unroll
        for (int n = 0; n < 4; ++n) {
          const int f = bn * BNT + wc * 64 + n * 16 + (lane & 15);
          Cf[(size_t)i * N + f] = acc[m][n][j];
        }
      }
    }
  }
}

// Flash attention: grid (T/64, B*H), 256 thr = 4 waves x 16 q-rows.
// q,k,v: [B,H,T,D] bf16 (Q pre-scaled by 1/8). ao: [B,T,C] bf16.
__global__ __launch_bounds__(256)
void attn_kernel(const u16* __restrict__ q, const u16* __restrict__ k,
                 const u16* __restrict__ v, u16* __restrict__ ao) {
  __shared__ u16 Klds[64 * 72];       // rows padded to 144B -> 2-way (free)
  __shared__ u16 VT[64 * 72];         // V transposed [d][kv]
  __shared__ u16 Plds[4 * 16 * 72];   // per-wave P tiles
  const int tid = threadIdx.x, lane = tid & 63, w = tid >> 6;
  const int qi = blockIdx.x, bh = blockIdx.y;
  const int b = bh >> 4, h = bh & 15;
  const size_t hb = (size_t)bh * 2048 * 64;

  s8b qf[2];
  {
    const int row = qi * 64 + w * 16 + (lane & 15);
    const u16* qp = q + hb + (size_t)row * 64 + (lane >> 4) * 8;
    qf[0] = *(const s8b*)qp;
    qf[1] = *(const s8b*)(qp + 32);
  }
  f4 acc[4] = {};
  float mrun[4], lrun[4];
#pragma unroll
  for (int j = 0; j < 4; ++j) { mrun[j] = -1e30f; lrun[j] = 0.f; }

  for (int kt = 0; kt <= qi; ++kt) {
    __syncthreads();
#pragma unroll
    for (int c0 = 0; c0 < 2; ++c0) {
      const int c = tid + c0 * 256;
      const int r = c >> 3, sl = c & 7;
      const size_t rg = hb + (size_t)(kt * 64 + r) * 64 + sl * 8;
      *(s8b*)(&Klds[r * 72 + sl * 8]) = *(const s8b*)(k + rg);
      const s8b vv = *(const s8b*)(v + rg);
#pragma unroll
      for (int e = 0; e < 8; ++e) VT[(sl * 8 + e) * 72 + r] = (u16)vv[e];
    }
    __syncthreads();

    f4 s[4];
#pragma unroll
    for (int n = 0; n < 4; ++n) {
      f4 z = {};
#pragma unroll
      for (int kk = 0; kk < 2; ++kk) {
        const int row = n * 16 + (lane & 15);
        const s8b kf = *(const s8b*)(&Klds[row * 72 + kk * 32 + (lane >> 4) * 8]);
        z = __builtin_amdgcn_mfma_f32_16x16x32_bf16(qf[kk], kf, z, 0, 0, 0);
      }
      s[n] = z;
    }
    if (kt == qi) {
      const int ql = w * 16 + (lane >> 4) * 4;
#pragma unroll
      for (int n = 0; n < 4; ++n) {
        const int kl = n * 16 + (lane & 15);
#pragma unroll
        for (int j = 0; j < 4; ++j)
          if (kl > ql + j) s[n][j] = -1e30f;
      }
    }
    float p[4][4];
#pragma unroll
    for (int j = 0; j < 4; ++j) {
      float tm = fmaxf(fmaxf(s[0][j], s[1][j]), fmaxf(s[2][j], s[3][j]));
#pragma unroll
      for (int d = 1; d < 16; d <<= 1) tm = fmaxf(tm, __shfl_xor(tm, d));
      const float mnew = fmaxf(mrun[j], tm);
      const float alpha = __expf(mrun[j] - mnew);
      float ts = 0.f;
#pragma unroll
      for (int n = 0; n < 4; ++n) { p[n][j] = __expf(s[n][j] - mnew); ts += p[n][j]; }
#pragma unroll
      for (int d = 1; d < 16; d <<= 1) ts += __shfl_xor(ts, d);
      lrun[j] = lrun[j] * alpha + ts;
      mrun[j] = mnew;
#pragma unroll
      for (int dn = 0; dn < 4; ++dn) acc[dn][j] *= alpha;
    }
    u16* pw = &Plds[w * 16 * 72];
#pragma unroll
    for (int n = 0; n < 4; ++n)
#pragma unroll
      for (int j = 0; j < 4; ++j)
        pw[((lane >> 4) * 4 + j) * 72 + n * 16 + (lane & 15)] = f2bf(p[n][j]);
#pragma unroll
    for (int dn = 0; dn < 4; ++dn) {
#pragma unroll
      for (int kk = 0; kk < 2; ++kk) {
        const s8b pf = *(const s8b*)(&pw[(lane & 15) * 72 + kk * 32 + (lane >> 4) * 8]);
        const s8b vf = *(const s8b*)(&VT[(dn * 16 + (lane & 15)) * 72 + kk * 32 + (lane >> 4) * 8]);
        acc[dn] = __builtin_amdgcn_mfma_f32_16x16x32_bf16(pf, vf, acc[dn], 0, 0, 0);
      }
    }
  }
#pragma unroll
  for (int j = 0; j < 4; ++j) {
    const int t = qi * 64 + w * 16 + (lane >> 4) * 4 + j;
    const float rl = 1.0f / lrun[j];
#pragma unroll
    for (int dn = 0; dn < 4; ++dn) {
      const int d = dn * 16 + (lane & 15);
      ao[((size_t)(b * 2048 + t)) * 1024 + h * 64 + d] = f2bf(acc[dn][j] * rl);
    }
  }
}

extern "C" void kernel_launch(void* const* d_in, const int* in_sizes, int n_in,
                              void* d_out, int out_size, void* d_ws, size_t ws_size,
                              hipStream_t stream) {
  const float* x = (const float*)d_in[0];
  const float* w_attn = (const float*)d_in[1];
  const float* w_proj = (const float*)d_in[2];
  float* out = (float*)d_out;
  char* ws = (char*)d_ws;

  // workspace layout (bytes): xb/ao 0..16M, wab 16..22M, wpb 22..24M,
  // q 24..40M, k 40..56M, v 56..72M
  u16* xb  = (u16*)(ws);
  u16* wab = (u16*)(ws + (22u << 20) - (6u << 20));
  u16* wpb = (u16*)(ws + (22u << 20));
  u16* qb  = (u16*)(ws + (24u << 20));
  u16* kb  = (u16*)(ws + (40u << 20));
  u16* vb  = (u16*)(ws + (56u << 20));
  u16* ao  = xb;  // alias: xb dead after GEMM1

  cvt_kernel<<<8192, 256, 0, stream>>>(x, xb, 2097152);        // 8192*1024 /4
  cvt_kernel<<<3072, 256, 0, stream>>>(w_attn, wab, 786432);   // 3072*1024 /4
  cvt_kernel<<<1024, 256, 0, stream>>>(w_proj, wpb, 262144);   // 1024*1024 /4

  gemm_bt<0><<<dim3(24, 64), 256, 0, stream>>>(xb, wab, nullptr, qb, kb, vb,
                                               8192, 3072, 1024);
  attn_kernel<<<dim3(32, 64), 256, 0, stream>>>(qb, kb, vb, ao);
  gemm_bt<1><<<dim3(8, 64), 256, 0, stream>>>(ao, wpb, out, nullptr, nullptr, nullptr,
                                              8192, 1024, 1024);
}

// Round 2
// 317.160 us; speedup vs baseline: 1.3345x; 1.3345x over previous
//
#include <hip/hip_runtime.h>

typedef __attribute__((ext_vector_type(8))) short s8b;
typedef __attribute__((ext_vector_type(4))) float f4;
typedef unsigned short u16;

__device__ __forceinline__ u16 f2bf(float f) {
  union { float f; unsigned u; } x; x.f = f;
  unsigned r = x.u + 0x7fffu + ((x.u >> 16) & 1u);
  return (u16)(r >> 16);
}

__device__ __forceinline__ void gload16(const void* g, void* l) {
  __builtin_amdgcn_global_load_lds(
      (const __attribute__((address_space(1))) void*)g,
      (__attribute__((address_space(3))) void*)l, 16, 0, 0);
}

__global__ void cvt_kernel(const float* __restrict__ in, u16* __restrict__ out, int n4) {
  int i = blockIdx.x * blockDim.x + threadIdx.x;
  if (i < n4) {
    const float4 v = ((const float4*)in)[i];
    ushort4 o;
    o.x = f2bf(v.x); o.y = f2bf(v.y); o.z = f2bf(v.z); o.w = f2bf(v.w);
    ((ushort4*)out)[i] = o;
  }
}

// C[M,N] = A[M,K] * B[N,K]^T  (both row-major bf16), fp32 accum.
#define BMT 128
#define BNT 128
#define BKT 64

template<int MODE>
__global__ __launch_bounds__(256, 2)
void gemm_bt(const u16* __restrict__ A, const u16* __restrict__ Bm,
             float* __restrict__ Cf,
             u16* __restrict__ qo, u16* __restrict__ ko, u16* __restrict__ vo,
             int M, int N, int K) {
  __shared__ u16 lds[2][2][BMT * BKT];
  const int tid = threadIdx.x;
  const int lane = tid & 63;
  const int w = tid >> 6;
  const int wr = w >> 1, wc = w & 1;
  const int bm = blockIdx.y, bn = blockIdx.x;
  const int ric = lane >> 3;
  const int ssw = (lane & 7) ^ ric;

  const u16* Ab = A + (size_t)bm * BMT * K;
  const u16* Bb = Bm + (size_t)bn * BNT * K;

  f4 acc[4][4] = {};

  auto stage = [&](int sbuf, int kt) {
    const int ko_ = kt * BKT;
#pragma unroll
    for (int c = 0; c < 4; ++c) {
      const int rch = w * 32 + c * 8;
      gload16(Ab + (size_t)(rch + ric) * K + ko_ + ssw * 8, &lds[sbuf][0][rch * BKT]);
      gload16(Bb + (size_t)(rch + ric) * K + ko_ + ssw * 8, &lds[sbuf][1][rch * BKT]);
    }
  };

  auto compute = [&](int cbuf) {
    const u16* At = &lds[cbuf][0][0];
    const u16* Bt = &lds[cbuf][1][0];
#pragma unroll
    for (int kk = 0; kk < 2; ++kk) {
      s8b a[4], b[4];
#pragma unroll
      for (int m = 0; m < 4; ++m) {
        const int row = wr * 64 + m * 16 + (lane & 15);
        a[m] = *(const s8b*)(At + row * BKT + ((((kk << 2) + (lane >> 4)) ^ (row & 7)) << 3));
      }
#pragma unroll
      for (int n = 0; n < 4; ++n) {
        const int row = wc * 64 + n * 16 + (lane & 15);
        b[n] = *(const s8b*)(Bt + row * BKT + ((((kk << 2) + (lane >> 4)) ^ (row & 7)) << 3));
      }
#pragma unroll
      for (int m = 0; m < 4; ++m)
#pragma unroll
        for (int n = 0; n < 4; ++n)
          acc[m][n] = __builtin_amdgcn_mfma_f32_16x16x32_bf16(a[m], b[n], acc[m][n], 0, 0, 0);
    }
  };

  const int nk = K / BKT;
  stage(0, 0);
  __syncthreads();
  int buf = 0;
  for (int kt = 0; kt < nk - 1; ++kt) {
    stage(buf ^ 1, kt + 1);
    compute(buf);
    __syncthreads();
    buf ^= 1;
  }
  compute(buf);

  if (MODE == 0) {
#pragma unroll
    for (int n = 0; n < 4; ++n) {
      const int f = bn * BNT + wc * 64 + n * 16 + (lane & 15);
      const int which = f >> 10;
      const int rem = f & 1023;
      const int h = rem >> 6, d = rem & 63;
      u16* dst = which == 0 ? qo : (which == 1 ? ko : vo);
      const float sc = which == 0 ? 0.125f : 1.0f;
#pragma unroll
      for (int m = 0; m < 4; ++m) {
#pragma unroll
        for (int j = 0; j < 4; ++j) {
          const int i = bm * BMT + wr * 64 + m * 16 + (lane >> 4) * 4 + j;
          const int bb = i >> 11, t = i & 2047;
          dst[((size_t)((bb << 4) + h) * 2048 + t) * 64 + d] = f2bf(acc[m][n][j] * sc);
        }
      }
    }
  } else {
#pragma unroll
    for (int m = 0; m < 4; ++m) {
#pragma unroll
      for (int j = 0; j < 4; ++j) {
        const int i = bm * BMT + wr * 64 + m * 16 + (lane >> 4) * 4 + j;
#pragma unroll
        for (int n = 0; n < 4; ++n) {
          const int f = bn * BNT + wc * 64 + n * 16 + (lane & 15);
          Cf[(size_t)i * N + f] = acc[m][n][j];
        }
      }
    }
  }
}

// Flash attention: grid (T/64, B*H), 256 thr = 4 waves x 16 q-rows.
// All LDS tiles stride-64 elems + XOR chunk swizzle: chunk ^= (row&7)^(row>>3)
// (P uses rows 0..15 so row>>3 folds in automatically via same formula).
__global__ __launch_bounds__(256, 3)
void attn_kernel(const u16* __restrict__ q, const u16* __restrict__ k,
                 const u16* __restrict__ v, u16* __restrict__ ao) {
  __shared__ u16 Kl[2][64 * 64];
  __shared__ u16 VTl[2][64 * 64];
  __shared__ u16 Pl[4][16 * 64];
  const int tid = threadIdx.x, lane = tid & 63, w = tid >> 6;
  const int qi = blockIdx.x, bh = blockIdx.y;
  const int b = bh >> 4, h = bh & 15;
  const size_t hb = (size_t)bh * 2048 * 64;

  s8b qf[2];
  {
    const int row = qi * 64 + w * 16 + (lane & 15);
    const u16* qp = q + hb + (size_t)row * 64 + (lane >> 4) * 8;
    qf[0] = *(const s8b*)qp;
    qf[1] = *(const s8b*)(qp + 32);
  }
  f4 acc[4] = {};
  float mrun[4], lrun[4];
#pragma unroll
  for (int j = 0; j < 4; ++j) { mrun[j] = -1e30f; lrun[j] = 0.f; }

  const int r0 = tid >> 3, sl = tid & 7;   // chunk 0: rows 0..31; chunk 1: rows 32..63
  s8b kr[2], vr[2];

  auto load_regs = [&](int kt) {
    const size_t base = hb + (size_t)kt * 64 * 64;
    const u16* kp = k + base + (size_t)r0 * 64 + sl * 8;
    const u16* vp = v + base + (size_t)r0 * 64 + sl * 8;
    kr[0] = *(const s8b*)kp;
    vr[0] = *(const s8b*)vp;
    kr[1] = *(const s8b*)(kp + 32 * 64);
    vr[1] = *(const s8b*)(vp + 32 * 64);
  };

  auto write_lds = [&](int bu) {
#pragma unroll
    for (int c0 = 0; c0 < 2; ++c0) {
      const int r = r0 + c0 * 32;
      // K[row=r][cols sl*8..+7]
      *(s8b*)(&Kl[bu][r * 64 + ((sl ^ (r & 7) ^ (r >> 3)) << 3)]) = kr[c0];
      // VT[row=sl*8+e][col=r]: row&7 = e, row>>3 = sl
#pragma unroll
      for (int e = 0; e < 8; ++e)
        VTl[bu][(sl * 8 + e) * 64 + ((((r >> 3) ^ e ^ sl)) << 3) + (r & 7)] = (u16)vr[c0][e];
    }
  };

  load_regs(0);
  write_lds(0);
  __syncthreads();
  int bu = 0;

  for (int kt = 0; kt <= qi; ++kt) {
    if (kt < qi) load_regs(kt + 1);

    // ---- QK^T ----
    f4 s[4];
    __builtin_amdgcn_s_setprio(1);
#pragma unroll
    for (int n = 0; n < 4; ++n) {
      f4 z = {};
#pragma unroll
      for (int kk = 0; kk < 2; ++kk) {
        const int row = n * 16 + (lane & 15);
        const s8b kf = *(const s8b*)(
            &Kl[bu][row * 64 + ((((kk << 2) + (lane >> 4)) ^ (row & 7) ^ (row >> 3)) << 3)]);
        z = __builtin_amdgcn_mfma_f32_16x16x32_bf16(qf[kk], kf, z, 0, 0, 0);
      }
      s[n] = z;
    }
    __builtin_amdgcn_s_setprio(0);

    if (kt == qi) {
      const int ql = w * 16 + (lane >> 4) * 4;
#pragma unroll
      for (int n = 0; n < 4; ++n) {
        const int kl = n * 16 + (lane & 15);
#pragma unroll
        for (int j = 0; j < 4; ++j)
          if (kl > ql + j) s[n][j] = -1e30f;
      }
    }

    // ---- online softmax ----
    float p[4][4];
#pragma unroll
    for (int j = 0; j < 4; ++j) {
      float tm = fmaxf(fmaxf(s[0][j], s[1][j]), fmaxf(s[2][j], s[3][j]));
#pragma unroll
      for (int d = 1; d < 16; d <<= 1) tm = fmaxf(tm, __shfl_xor(tm, d));
      const float mnew = fmaxf(mrun[j], tm);
      const float alpha = __expf(mrun[j] - mnew);
      float ts = 0.f;
#pragma unroll
      for (int n = 0; n < 4; ++n) { p[n][j] = __expf(s[n][j] - mnew); ts += p[n][j]; }
#pragma unroll
      for (int d = 1; d < 16; d <<= 1) ts += __shfl_xor(ts, d);
      lrun[j] = lrun[j] * alpha + ts;
      mrun[j] = mnew;
#pragma unroll
      for (int dn = 0; dn < 4; ++dn) acc[dn][j] *= alpha;
    }

    // ---- P -> LDS (swizzled) ----
    u16* pw = &Pl[w][0];
#pragma unroll
    for (int n = 0; n < 4; ++n) {
#pragma unroll
      for (int j = 0; j < 4; ++j) {
        const int prow = (lane >> 4) * 4 + j;
        const int pcol = n * 16 + (lane & 15);
        pw[prow * 64 + ((((pcol >> 3) ^ (prow & 7) ^ (prow >> 3))) << 3) + (pcol & 7)] =
            f2bf(p[n][j]);
      }
    }

    // ---- PV ----
    __builtin_amdgcn_s_setprio(1);
#pragma unroll
    for (int dn = 0; dn < 4; ++dn) {
#pragma unroll
      for (int kk = 0; kk < 2; ++kk) {
        const int prow = lane & 15;
        const s8b pf = *(const s8b*)(
            &pw[prow * 64 + ((((kk << 2) + (lane >> 4)) ^ (prow & 7) ^ (prow >> 3)) << 3)]);
        const int vrow = dn * 16 + (lane & 15);
        const s8b vf = *(const s8b*)(
            &VTl[bu][vrow * 64 + ((((kk << 2) + (lane >> 4)) ^ (vrow & 7) ^ (vrow >> 3)) << 3)]);
        acc[dn] = __builtin_amdgcn_mfma_f32_16x16x32_bf16(pf, vf, acc[dn], 0, 0, 0);
      }
    }
    __builtin_amdgcn_s_setprio(0);

    if (kt < qi) write_lds(bu ^ 1);
    __syncthreads();
    bu ^= 1;
  }

#pragma unroll
  for (int j = 0; j < 4; ++j) {
    const int t = qi * 64 + w * 16 + (lane >> 4) * 4 + j;
    const float rl = 1.0f / lrun[j];
#pragma unroll
    for (int dn = 0; dn < 4; ++dn) {
      const int d = dn * 16 + (lane & 15);
      ao[((size_t)(b * 2048 + t)) * 1024 + h * 64 + d] = f2bf(acc[dn][j] * rl);
    }
  }
}

extern "C" void kernel_launch(void* const* d_in, const int* in_sizes, int n_in,
                              void* d_out, int out_size, void* d_ws, size_t ws_size,
                              hipStream_t stream) {
  const float* x = (const float*)d_in[0];
  const float* w_attn = (const float*)d_in[1];
  const float* w_proj = (const float*)d_in[2];
  float* out = (float*)d_out;
  char* ws = (char*)d_ws;

  u16* xb  = (u16*)(ws);
  u16* wab = (u16*)(ws + (16u << 20));
  u16* wpb = (u16*)(ws + (22u << 20));
  u16* qb  = (u16*)(ws + (24u << 20));
  u16* kb  = (u16*)(ws + (40u << 20));
  u16* vb  = (u16*)(ws + (56u << 20));
  u16* ao  = xb;  // alias: xb dead after GEMM1

  cvt_kernel<<<8192, 256, 0, stream>>>(x, xb, 2097152);
  cvt_kernel<<<3072, 256, 0, stream>>>(w_attn, wab, 786432);
  cvt_kernel<<<1024, 256, 0, stream>>>(w_proj, wpb, 262144);

  gemm_bt<0><<<dim3(24, 64), 256, 0, stream>>>(xb, wab, nullptr, qb, kb, vb,
                                               8192, 3072, 1024);
  attn_kernel<<<dim3(32, 64), 256, 0, stream>>>(qb, kb, vb, ao);
  gemm_bt<1><<<dim3(8, 64), 256, 0, stream>>>(ao, wpb, out, nullptr, nullptr, nullptr,
                                              8192, 1024, 1024);
}

// Round 3
// 215.851 us; speedup vs baseline: 1.9609x; 1.4694x over previous
//
#include <hip/hip_runtime.h>
#include <hip/hip_bf16.h>

typedef __attribute__((ext_vector_type(8))) short s8b;
typedef __attribute__((ext_vector_type(4))) float f4;
typedef unsigned short u16;

__device__ __forceinline__ u16 f2bf(float f) {
  union { float f; unsigned u; } x; x.f = f;
  unsigned r = x.u + 0x7fffu + ((x.u >> 16) & 1u);
  return (u16)(r >> 16);
}

__device__ __forceinline__ void gload16(const void* g, void* l) {
  __builtin_amdgcn_global_load_lds(
      (const __attribute__((address_space(1))) void*)g,
      (__attribute__((address_space(3))) void*)l, 16, 0, 0);
}

__global__ void cvt_kernel(const float* __restrict__ in, u16* __restrict__ out, int n4) {
  int i = blockIdx.x * blockDim.x + threadIdx.x;
  if (i < n4) {
    const float4 v = ((const float4*)in)[i];
    ushort4 o;
    o.x = f2bf(v.x); o.y = f2bf(v.y); o.z = f2bf(v.z); o.w = f2bf(v.w);
    ((ushort4*)out)[i] = o;
  }
}

// C[M,N] = A[M,K] * B[N,K]^T  (both row-major bf16), fp32 accum.
#define BMT 128
#define BNT 128
#define BKT 64

template<int MODE>
__global__ __launch_bounds__(256, 2)
void gemm_bt(const u16* __restrict__ A, const u16* __restrict__ Bm,
             float* __restrict__ Cf,
             u16* __restrict__ qo, u16* __restrict__ ko, u16* __restrict__ vo,
             int M, int N, int K) {
  __shared__ u16 lds[2][2][BMT * BKT];
  const int tid = threadIdx.x;
  const int lane = tid & 63;
  const int w = tid >> 6;
  const int wr = w >> 1, wc = w & 1;
  const int bm = blockIdx.y, bn = blockIdx.x;
  const int ric = lane >> 3;
  const int ssw = (lane & 7) ^ ric;

  const u16* Ab = A + (size_t)bm * BMT * K;
  const u16* Bb = Bm + (size_t)bn * BNT * K;

  f4 acc[4][4] = {};

  auto stage = [&](int sbuf, int kt) {
    const int ko_ = kt * BKT;
#pragma unroll
    for (int c = 0; c < 4; ++c) {
      const int rch = w * 32 + c * 8;
      gload16(Ab + (size_t)(rch + ric) * K + ko_ + ssw * 8, &lds[sbuf][0][rch * BKT]);
      gload16(Bb + (size_t)(rch + ric) * K + ko_ + ssw * 8, &lds[sbuf][1][rch * BKT]);
    }
  };

  auto compute = [&](int cbuf) {
    const u16* At = &lds[cbuf][0][0];
    const u16* Bt = &lds[cbuf][1][0];
#pragma unroll
    for (int kk = 0; kk < 2; ++kk) {
      s8b a[4], b[4];
#pragma unroll
      for (int m = 0; m < 4; ++m) {
        const int row = wr * 64 + m * 16 + (lane & 15);
        a[m] = *(const s8b*)(At + row * BKT + ((((kk << 2) + (lane >> 4)) ^ (row & 7)) << 3));
      }
#pragma unroll
      for (int n = 0; n < 4; ++n) {
        const int row = wc * 64 + n * 16 + (lane & 15);
        b[n] = *(const s8b*)(Bt + row * BKT + ((((kk << 2) + (lane >> 4)) ^ (row & 7)) << 3));
      }
#pragma unroll
      for (int m = 0; m < 4; ++m)
#pragma unroll
        for (int n = 0; n < 4; ++n)
          acc[m][n] = __builtin_amdgcn_mfma_f32_16x16x32_bf16(a[m], b[n], acc[m][n], 0, 0, 0);
    }
  };

  const int nk = K / BKT;
  stage(0, 0);
  __syncthreads();
  int buf = 0;
  for (int kt = 0; kt < nk - 1; ++kt) {
    stage(buf ^ 1, kt + 1);
    compute(buf);
    __syncthreads();
    buf ^= 1;
  }
  compute(buf);

  if (MODE == 0) {
#pragma unroll
    for (int n = 0; n < 4; ++n) {
      const int f = bn * BNT + wc * 64 + n * 16 + (lane & 15);
      const int which = f >> 10;
      const int rem = f & 1023;
      const int h = rem >> 6, d = rem & 63;
      u16* dst = which == 0 ? qo : (which == 1 ? ko : vo);
      const float sc = which == 0 ? 0.125f : 1.0f;
#pragma unroll
      for (int m = 0; m < 4; ++m) {
#pragma unroll
        for (int j = 0; j < 4; ++j) {
          const int i = bm * BMT + wr * 64 + m * 16 + (lane >> 4) * 4 + j;
          const int bb = i >> 11, t = i & 2047;
          const u16 val = f2bf(acc[m][n][j] * sc);
          if (which == 2)
            vo[((size_t)((bb << 4) + h) * 64 + d) * 2048 + t] = val;   // V^T layout
          else
            dst[((size_t)((bb << 4) + h) * 2048 + t) * 64 + d] = val;
        }
      }
    }
  } else {
#pragma unroll
    for (int m = 0; m < 4; ++m) {
#pragma unroll
      for (int j = 0; j < 4; ++j) {
        const int i = bm * BMT + wr * 64 + m * 16 + (lane >> 4) * 4 + j;
#pragma unroll
        for (int n = 0; n < 4; ++n) {
          const int f = bn * BNT + wc * 64 + n * 16 + (lane & 15);
          Cf[(size_t)i * N + f] = acc[m][n][j];
        }
      }
    }
  }
}

// Flash attention, swapped-QK^T (S^T = K·Q^T), grid (16, B*H).
// Each block handles q-tile pair (x, 31-x) -> uniform 33 tile-steps.
// q,k: [B,H,T,D] bf16 (Q pre-scaled 1/8); vt: [B,H,D,T] bf16; ao: [B,T,C] bf16.
__global__ __launch_bounds__(256, 3)
void attn_kernel(const u16* __restrict__ q, const u16* __restrict__ k,
                 const u16* __restrict__ vt, u16* __restrict__ ao) {
  __shared__ u16 Kl[2][64 * 64];
  __shared__ u16 VTl[2][64 * 64];
  __shared__ u16 Pl[4][16 * 64];
  const int tid = threadIdx.x, lane = tid & 63, w = tid >> 6;
  const int bh = blockIdx.y;
  const int b = bh >> 4, h = bh & 15;
  const size_t hb = (size_t)bh * 2048 * 64;
  const int qlo = lane & 15, hi = lane >> 4;
  const int r0 = tid >> 3, sl = tid & 7;
  u16* pw = &Pl[w][0];

  s8b kr[2], vr[2];
  auto load_regs = [&](int kt) {
    const u16* kp = k + hb + (size_t)(kt * 64 + r0) * 64 + sl * 8;
    kr[0] = *(const s8b*)kp;
    kr[1] = *(const s8b*)(kp + 32 * 64);
    const u16* vp = vt + hb + (size_t)r0 * 2048 + kt * 64 + sl * 8;
    vr[0] = *(const s8b*)vp;
    vr[1] = *(const s8b*)(vp + 32 * 2048);
  };
  auto write_lds = [&](int bu) {
#pragma unroll
    for (int c0 = 0; c0 < 2; ++c0) {
      const int r = r0 + c0 * 32;
      const int off = r * 64 + ((sl ^ (r & 7) ^ (r >> 3)) << 3);
      *(s8b*)(&Kl[bu][off]) = kr[c0];
      *(s8b*)(&VTl[bu][off]) = vr[c0];
    }
  };

  for (int ph = 0; ph < 2; ++ph) {
    const int qi = ph ? 31 - blockIdx.x : blockIdx.x;
    s8b qf[2];
    {
      const u16* qp = q + hb + (size_t)(qi * 64 + w * 16 + qlo) * 64 + hi * 8;
      qf[0] = *(const s8b*)qp;
      qf[1] = *(const s8b*)(qp + 32);
    }
    f4 acc[4] = {};
    float mrun = -1e30f, lrun = 0.f;

    load_regs(0);
    write_lds(0);
    __syncthreads();
    int bu = 0;

    for (int kt = 0; kt <= qi; ++kt) {
      if (kt < qi) load_regs(kt + 1);

      // ---- S^T = K·Q^T : lane owns q-row (lane&15), k = n*16 + hi*4 + j ----
      f4 s[4] = {};
      __builtin_amdgcn_s_setprio(1);
#pragma unroll
      for (int n = 0; n < 4; ++n) {
        const int row = n * 16 + qlo;
        const int swz = (row & 7) ^ (row >> 3);
#pragma unroll
        for (int kk = 0; kk < 2; ++kk) {
          const s8b kf = *(const s8b*)(&Kl[bu][row * 64 + ((((kk << 2) + hi) ^ swz) << 3)]);
          s[n] = __builtin_amdgcn_mfma_f32_16x16x32_bf16(kf, qf[kk], s[n], 0, 0, 0);
        }
      }
      __builtin_amdgcn_s_setprio(0);

      if (kt == qi) {
        const int qg = w * 16 + qlo;
#pragma unroll
        for (int n = 0; n < 4; ++n)
#pragma unroll
          for (int j = 0; j < 4; ++j)
            if (n * 16 + hi * 4 + j > qg) s[n][j] = -1e30f;
      }

      // ---- online softmax: in-lane + 2 shfls; defer-max THR=8 ----
      float tm = -1e30f;
#pragma unroll
      for (int n = 0; n < 4; ++n)
#pragma unroll
        for (int j = 0; j < 4; ++j) tm = fmaxf(tm, s[n][j]);
      tm = fmaxf(tm, __shfl_xor(tm, 16));
      tm = fmaxf(tm, __shfl_xor(tm, 32));
      const bool grow = __any(tm > mrun + 8.f);
      const float mnew = grow ? fmaxf(mrun, tm) : mrun;
      float ts = 0.f;
#pragma unroll
      for (int n = 0; n < 4; ++n)
#pragma unroll
        for (int j = 0; j < 4; ++j) {
          const float pv = __expf(s[n][j] - mnew);
          s[n][j] = pv;
          ts += pv;
        }
      ts += __shfl_xor(ts, 16);
      ts += __shfl_xor(ts, 32);
      if (grow) {
        const float alpha = __expf(mrun - mnew);
        lrun = lrun * alpha + ts;
        mrun = mnew;
        float af[4];
#pragma unroll
        for (int j = 0; j < 4; ++j) af[j] = __shfl(alpha, hi * 4 + j);
#pragma unroll
        for (int dn = 0; dn < 4; ++dn)
#pragma unroll
          for (int j = 0; j < 4; ++j) acc[dn][j] *= af[j];
      } else {
        lrun += ts;
      }

      // ---- pack P to bf16, b64-write to per-wave LDS (chunk-XOR swizzle) ----
#pragma unroll
      for (int n = 0; n < 4; ++n) {
        __hip_bfloat162 h0 = __float22bfloat162_rn(make_float2(s[n][0], s[n][1]));
        __hip_bfloat162 h1 = __float22bfloat162_rn(make_float2(s[n][2], s[n][3]));
        unsigned lo, hi2;
        __builtin_memcpy(&lo, &h0, 4);
        __builtin_memcpy(&hi2, &h1, 4);
        const unsigned long long w64 =
            (unsigned long long)lo | ((unsigned long long)hi2 << 32);
        const int cw = ((n << 2) + hi) ^ qlo;
        *(unsigned long long*)(pw + (qlo << 6) + (cw << 2)) = w64;
      }

      // ---- re-fragment P as A-operand: 4x ds_read_b64 ----
      union U8 { s8b v; unsigned long long u[2]; } pf[2];
#pragma unroll
      for (int kk = 0; kk < 2; ++kk) {
        const int ca = ((kk << 3) + (hi << 1)) ^ qlo;
        pf[kk].u[0] = *(const unsigned long long*)(pw + (qlo << 6) + (ca << 2));
        pf[kk].u[1] = *(const unsigned long long*)(pw + (qlo << 6) + ((ca ^ 1) << 2));
      }

      // ---- PV ----
      __builtin_amdgcn_s_setprio(1);
#pragma unroll
      for (int dn = 0; dn < 4; ++dn) {
        const int vrow = dn * 16 + qlo;
        const int vswz = (vrow & 7) ^ (vrow >> 3);
#pragma unroll
        for (int kk = 0; kk < 2; ++kk) {
          const s8b vf = *(const s8b*)(&VTl[bu][vrow * 64 + ((((kk << 2) + hi) ^ vswz) << 3)]);
          acc[dn] = __builtin_amdgcn_mfma_f32_16x16x32_bf16(pf[kk].v, vf, acc[dn], 0, 0, 0);
        }
      }
      __builtin_amdgcn_s_setprio(0);

      if (kt < qi) write_lds(bu ^ 1);
      __syncthreads();
      bu ^= 1;
    }

    const float rl = 1.0f / lrun;
    float rlb[4];
#pragma unroll
    for (int j = 0; j < 4; ++j) rlb[j] = __shfl(rl, hi * 4 + j);
#pragma unroll
    for (int j = 0; j < 4; ++j) {
      const int t = qi * 64 + w * 16 + hi * 4 + j;
#pragma unroll
      for (int dn = 0; dn < 4; ++dn) {
        const int d = dn * 16 + qlo;
        ao[((size_t)(b * 2048 + t)) * 1024 + h * 64 + d] = f2bf(acc[dn][j] * rlb[j]);
      }
    }
  }
}

extern "C" void kernel_launch(void* const* d_in, const int* in_sizes, int n_in,
                              void* d_out, int out_size, void* d_ws, size_t ws_size,
                              hipStream_t stream) {
  const float* x = (const float*)d_in[0];
  const float* w_attn = (const float*)d_in[1];
  const float* w_proj = (const float*)d_in[2];
  float* out = (float*)d_out;
  char* ws = (char*)d_ws;

  u16* xb  = (u16*)(ws);
  u16* wab = (u16*)(ws + (16u << 20));
  u16* wpb = (u16*)(ws + (22u << 20));
  u16* qb  = (u16*)(ws + (24u << 20));
  u16* kb  = (u16*)(ws + (40u << 20));
  u16* vb  = (u16*)(ws + (56u << 20));   // V^T [B,H,D,T]
  u16* ao  = xb;  // alias: xb dead after GEMM1

  cvt_kernel<<<8192, 256, 0, stream>>>(x, xb, 2097152);
  cvt_kernel<<<3072, 256, 0, stream>>>(w_attn, wab, 786432);
  cvt_kernel<<<1024, 256, 0, stream>>>(w_proj, wpb, 262144);

  gemm_bt<0><<<dim3(24, 64), 256, 0, stream>>>(xb, wab, nullptr, qb, kb, vb,
                                               8192, 3072, 1024);
  attn_kernel<<<dim3(16, 64), 256, 0, stream>>>(qb, kb, vb, ao);
  gemm_bt<1><<<dim3(8, 64), 256, 0, stream>>>(ao, wpb, out, nullptr, nullptr, nullptr,
                                              8192, 1024, 1024);
}

// Round 4
// 185.034 us; speedup vs baseline: 2.2874x; 1.1665x over previous
//
#include <hip/hip_runtime.h>
#include <hip/hip_bf16.h>

typedef __attribute__((ext_vector_type(8))) short s8b;
typedef __attribute__((ext_vector_type(4))) float f4;
typedef unsigned short u16;

__device__ __forceinline__ u16 f2bf(float f) {
  union { float f; unsigned u; } x; x.f = f;
  unsigned r = x.u + 0x7fffu + ((x.u >> 16) & 1u);
  return (u16)(r >> 16);
}

__device__ __forceinline__ void gload16(const void* g, void* l) {
  __builtin_amdgcn_global_load_lds(
      (const __attribute__((address_space(1))) void*)g,
      (__attribute__((address_space(3))) void*)l, 16, 0, 0);
}

__global__ void cvt_kernel(const float* __restrict__ in, u16* __restrict__ out, int n4) {
  int i = blockIdx.x * blockDim.x + threadIdx.x;
  if (i < n4) {
    const float4 v = ((const float4*)in)[i];
    ushort4 o;
    o.x = f2bf(v.x); o.y = f2bf(v.y); o.z = f2bf(v.z); o.w = f2bf(v.w);
    ((ushort4*)out)[i] = o;
  }
}

// C[M,N] = A[M,K] * B[N,K]^T  (both row-major bf16), fp32 accum.
// 1-D grid of GX*64 blocks; XCD-affine remap groups same-bm blocks per XCD.
#define BMT 128
#define BNT 128
#define BKT 64

template<int MODE>
__global__ __launch_bounds__(256, 2)
void gemm_bt(const u16* __restrict__ A, const u16* __restrict__ Bm,
             float* __restrict__ Cf,
             u16* __restrict__ qo, u16* __restrict__ ko, u16* __restrict__ vo,
             int N, int K, int GX) {
  __shared__ u16 lds[2][2][BMT * BKT];
  const int tid = threadIdx.x;
  const int lane = tid & 63;
  const int w = tid >> 6;
  const int wr = w >> 1, wc = w & 1;
  const int d = blockIdx.x;
  const int xcd = d & 7, ib = d >> 3;
  const int bm = xcd * 8 + ib / GX;
  const int bn = ib % GX;
  const int ric = lane >> 3;
  const int ssw = (lane & 7) ^ ric;

  const u16* Ab = A + (size_t)bm * BMT * K;
  const u16* Bb = Bm + (size_t)bn * BNT * K;

  f4 acc[4][4] = {};

  auto stage = [&](int sbuf, int kt) {
    const int ko_ = kt * BKT;
#pragma unroll
    for (int c = 0; c < 4; ++c) {
      const int rch = w * 32 + c * 8;
      gload16(Ab + (size_t)(rch + ric) * K + ko_ + ssw * 8, &lds[sbuf][0][rch * BKT]);
      gload16(Bb + (size_t)(rch + ric) * K + ko_ + ssw * 8, &lds[sbuf][1][rch * BKT]);
    }
  };

  auto compute = [&](int cbuf) {
    const u16* At = &lds[cbuf][0][0];
    const u16* Bt = &lds[cbuf][1][0];
#pragma unroll
    for (int kk = 0; kk < 2; ++kk) {
      s8b a[4], b[4];
#pragma unroll
      for (int m = 0; m < 4; ++m) {
        const int row = wr * 64 + m * 16 + (lane & 15);
        a[m] = *(const s8b*)(At + row * BKT + ((((kk << 2) + (lane >> 4)) ^ (row & 7)) << 3));
      }
#pragma unroll
      for (int n = 0; n < 4; ++n) {
        const int row = wc * 64 + n * 16 + (lane & 15);
        b[n] = *(const s8b*)(Bt + row * BKT + ((((kk << 2) + (lane >> 4)) ^ (row & 7)) << 3));
      }
#pragma unroll
      for (int m = 0; m < 4; ++m)
#pragma unroll
        for (int n = 0; n < 4; ++n)
          acc[m][n] = __builtin_amdgcn_mfma_f32_16x16x32_bf16(a[m], b[n], acc[m][n], 0, 0, 0);
    }
  };

  const int nk = K / BKT;
  stage(0, 0);
  __syncthreads();
  int buf = 0;
  for (int kt = 0; kt < nk - 1; ++kt) {
    stage(buf ^ 1, kt + 1);
    compute(buf);
    __syncthreads();
    buf ^= 1;
  }
  compute(buf);

  if (MODE == 0) {
#pragma unroll
    for (int n = 0; n < 4; ++n) {
      const int f = bn * BNT + wc * 64 + n * 16 + (lane & 15);
      const int which = f >> 10;
      const int rem = f & 1023;
      const int h = rem >> 6, dd = rem & 63;
      u16* dst = which == 0 ? qo : (which == 1 ? ko : vo);
      const float sc = which == 0 ? 0.125f : 1.0f;
#pragma unroll
      for (int m = 0; m < 4; ++m) {
#pragma unroll
        for (int j = 0; j < 4; ++j) {
          const int i = bm * BMT + wr * 64 + m * 16 + (lane >> 4) * 4 + j;
          const int bb = i >> 11, t = i & 2047;
          const u16 val = f2bf(acc[m][n][j] * sc);
          if (which == 2)
            vo[((size_t)((bb << 4) + h) * 64 + dd) * 2048 + t] = val;   // V^T layout
          else
            dst[((size_t)((bb << 4) + h) * 2048 + t) * 64 + dd] = val;
        }
      }
    }
  } else {
#pragma unroll
    for (int m = 0; m < 4; ++m) {
#pragma unroll
      for (int j = 0; j < 4; ++j) {
        const int i = bm * BMT + wr * 64 + m * 16 + (lane >> 4) * 4 + j;
#pragma unroll
        for (int n = 0; n < 4; ++n) {
          const int f = bn * BNT + wc * 64 + n * 16 + (lane & 15);
          Cf[(size_t)i * N + f] = acc[m][n][j];
        }
      }
    }
  }
}

// Flash attention, swapped-QK^T (S^T = K·Q^T), 1-D grid of 1024 blocks.
// XCD-affine remap: all 16 q-blocks of one bh land on one XCD (K/V L2-resident).
// Each block handles q-tile pair (x, 31-x) -> uniform 33 tile-steps.
// q,k: [B,H,T,D] bf16 (Q pre-scaled 1/8); vt: [B,H,D,T] bf16; ao: [B,T,C] bf16.
__global__ __launch_bounds__(256, 4)
void attn_kernel(const u16* __restrict__ q, const u16* __restrict__ k,
                 const u16* __restrict__ vt, u16* __restrict__ ao) {
  __shared__ u16 Kl[2][64 * 64];
  __shared__ u16 VTl[2][64 * 64];
  __shared__ u16 Pl[4][16 * 64];
  const int tid = threadIdx.x, lane = tid & 63, w = tid >> 6;
  const int dd = blockIdx.x;
  const int xcd = dd & 7, ib = dd >> 3;
  const int bh = xcd * 8 + (ib >> 4);
  const int qx = ib & 15;
  const int b = bh >> 4, h = bh & 15;
  const size_t hb = (size_t)bh * 2048 * 64;
  const int qlo = lane & 15, hi = lane >> 4;
  const int r0 = tid >> 3, sl = tid & 7;
  u16* pw = &Pl[w][0];

  s8b kr[2], vr[2];
  auto load_regs = [&](int kt) {
    const u16* kp = k + hb + (size_t)(kt * 64 + r0) * 64 + sl * 8;
    kr[0] = *(const s8b*)kp;
    kr[1] = *(const s8b*)(kp + 32 * 64);
    const u16* vp = vt + hb + (size_t)r0 * 2048 + kt * 64 + sl * 8;
    vr[0] = *(const s8b*)vp;
    vr[1] = *(const s8b*)(vp + 32 * 2048);
  };
  auto write_lds = [&](int bu) {
#pragma unroll
    for (int c0 = 0; c0 < 2; ++c0) {
      const int r = r0 + c0 * 32;
      const int off = r * 64 + ((sl ^ (r & 7) ^ (r >> 3)) << 3);
      *(s8b*)(&Kl[bu][off]) = kr[c0];
      *(s8b*)(&VTl[bu][off]) = vr[c0];
    }
  };

  for (int ph = 0; ph < 2; ++ph) {
    const int qi = ph ? 31 - qx : qx;
    s8b qf[2];
    {
      const u16* qp = q + hb + (size_t)(qi * 64 + w * 16 + qlo) * 64 + hi * 8;
      qf[0] = *(const s8b*)qp;
      qf[1] = *(const s8b*)(qp + 32);
    }
    f4 acc[4] = {};
    float mrun = -1e30f, lrun = 0.f;

    load_regs(0);
    write_lds(0);
    __syncthreads();
    int bu = 0;

    for (int kt = 0; kt <= qi; ++kt) {
      if (kt < qi) load_regs(kt + 1);

      // ---- S^T = K·Q^T : lane owns q-row (lane&15), k = n*16 + hi*4 + j ----
      f4 s[4] = {};
      __builtin_amdgcn_s_setprio(1);
#pragma unroll
      for (int n = 0; n < 4; ++n) {
        const int row = n * 16 + qlo;
        const int swz = (row & 7) ^ (row >> 3);
#pragma unroll
        for (int kk = 0; kk < 2; ++kk) {
          const s8b kf = *(const s8b*)(&Kl[bu][row * 64 + ((((kk << 2) + hi) ^ swz) << 3)]);
          s[n] = __builtin_amdgcn_mfma_f32_16x16x32_bf16(kf, qf[kk], s[n], 0, 0, 0);
        }
      }
      __builtin_amdgcn_s_setprio(0);

      if (kt == qi) {
        const int qg = w * 16 + qlo;
#pragma unroll
        for (int n = 0; n < 4; ++n)
#pragma unroll
          for (int j = 0; j < 4; ++j)
            if (n * 16 + hi * 4 + j > qg) s[n][j] = -1e30f;
      }

      // ---- online softmax: in-lane + 2 shfls; defer-max THR=8 ----
      float tm = -1e30f;
#pragma unroll
      for (int n = 0; n < 4; ++n)
#pragma unroll
        for (int j = 0; j < 4; ++j) tm = fmaxf(tm, s[n][j]);
      tm = fmaxf(tm, __shfl_xor(tm, 16));
      tm = fmaxf(tm, __shfl_xor(tm, 32));
      const bool grow = __any(tm > mrun + 8.f);
      const float mnew = grow ? fmaxf(mrun, tm) : mrun;
      float ts = 0.f;
#pragma unroll
      for (int n = 0; n < 4; ++n)
#pragma unroll
        for (int j = 0; j < 4; ++j) {
          const float pv = __expf(s[n][j] - mnew);
          s[n][j] = pv;
          ts += pv;
        }
      ts += __shfl_xor(ts, 16);
      ts += __shfl_xor(ts, 32);
      if (grow) {
        const float alpha = __expf(mrun - mnew);
        lrun = lrun * alpha + ts;
        mrun = mnew;
        float af[4];
#pragma unroll
        for (int j = 0; j < 4; ++j) af[j] = __shfl(alpha, hi * 4 + j);
#pragma unroll
        for (int dn = 0; dn < 4; ++dn)
#pragma unroll
          for (int j = 0; j < 4; ++j) acc[dn][j] *= af[j];
      } else {
        lrun += ts;
      }

      // ---- pack P to bf16, b64-write to per-wave LDS (chunk-XOR swizzle) ----
#pragma unroll
      for (int n = 0; n < 4; ++n) {
        __hip_bfloat162 h0 = __float22bfloat162_rn(make_float2(s[n][0], s[n][1]));
        __hip_bfloat162 h1 = __float22bfloat162_rn(make_float2(s[n][2], s[n][3]));
        unsigned lo, hi2;
        __builtin_memcpy(&lo, &h0, 4);
        __builtin_memcpy(&hi2, &h1, 4);
        const unsigned long long w64 =
            (unsigned long long)lo | ((unsigned long long)hi2 << 32);
        const int cw = ((n << 2) + hi) ^ qlo;
        *(unsigned long long*)(pw + (qlo << 6) + (cw << 2)) = w64;
      }

      // ---- re-fragment P as A-operand: 4x ds_read_b64 ----
      union U8 { s8b v; unsigned long long u[2]; } pf[2];
#pragma unroll
      for (int kk = 0; kk < 2; ++kk) {
        const int ca = ((kk << 3) + (hi << 1)) ^ qlo;
        pf[kk].u[0] = *(const unsigned long long*)(pw + (qlo << 6) + (ca << 2));
        pf[kk].u[1] = *(const unsigned long long*)(pw + (qlo << 6) + ((ca ^ 1) << 2));
      }

      // ---- PV ----
      __builtin_amdgcn_s_setprio(1);
#pragma unroll
      for (int dn = 0; dn < 4; ++dn) {
        const int vrow = dn * 16 + qlo;
        const int vswz = (vrow & 7) ^ (vrow >> 3);
#pragma unroll
        for (int kk = 0; kk < 2; ++kk) {
          const s8b vf = *(const s8b*)(&VTl[bu][vrow * 64 + ((((kk << 2) + hi) ^ vswz) << 3)]);
          acc[dn] = __builtin_amdgcn_mfma_f32_16x16x32_bf16(pf[kk].v, vf, acc[dn], 0, 0, 0);
        }
      }
      __builtin_amdgcn_s_setprio(0);

      if (kt < qi) write_lds(bu ^ 1);
      __syncthreads();
      bu ^= 1;
    }

    const float rl = 1.0f / lrun;
    float rlb[4];
#pragma unroll
    for (int j = 0; j < 4; ++j) rlb[j] = __shfl(rl, hi * 4 + j);
#pragma unroll
    for (int j = 0; j < 4; ++j) {
      const int t = qi * 64 + w * 16 + hi * 4 + j;
#pragma unroll
      for (int dn = 0; dn < 4; ++dn) {
        const int dcol = dn * 16 + qlo;
        ao[((size_t)(b * 2048 + t)) * 1024 + h * 64 + dcol] = f2bf(acc[dn][j] * rlb[j]);
      }
    }
  }
}

extern "C" void kernel_launch(void* const* d_in, const int* in_sizes, int n_in,
                              void* d_out, int out_size, void* d_ws, size_t ws_size,
                              hipStream_t stream) {
  const float* x = (const float*)d_in[0];
  const float* w_attn = (const float*)d_in[1];
  const float* w_proj = (const float*)d_in[2];
  float* out = (float*)d_out;
  char* ws = (char*)d_ws;

  u16* xb  = (u16*)(ws);
  u16* wab = (u16*)(ws + (16u << 20));
  u16* wpb = (u16*)(ws + (22u << 20));
  u16* qb  = (u16*)(ws + (24u << 20));
  u16* kb  = (u16*)(ws + (40u << 20));
  u16* vb  = (u16*)(ws + (56u << 20));   // V^T [B,H,D,T]
  u16* ao  = xb;  // alias: xb dead after GEMM1

  cvt_kernel<<<8192, 256, 0, stream>>>(x, xb, 2097152);
  cvt_kernel<<<3072, 256, 0, stream>>>(w_attn, wab, 786432);
  cvt_kernel<<<1024, 256, 0, stream>>>(w_proj, wpb, 262144);

  gemm_bt<0><<<1536, 256, 0, stream>>>(xb, wab, nullptr, qb, kb, vb,
                                       3072, 1024, 24);
  attn_kernel<<<1024, 256, 0, stream>>>(qb, kb, vb, ao);
  gemm_bt<1><<<512, 256, 0, stream>>>(ao, wpb, out, nullptr, nullptr, nullptr,
                                      1024, 1024, 8);
}